// Round 1
// baseline (197.899 us; speedup 1.0000x reference)
//
#include <hip/hip_runtime.h>
#include <hip/hip_bf16.h>
#include <math.h>

#define EMBED  768
#define SEQ    4096
#define ADIM   64
#define NBATCH 4

typedef __bf16 bf16;
typedef __attribute__((ext_vector_type(8))) __bf16 bf16x8;
typedef __attribute__((ext_vector_type(4))) __bf16 bf16x4;
typedef __attribute__((ext_vector_type(4))) float f32x4;

__device__ __forceinline__ f32x4 mfma16(bf16x8 a, bf16x8 b, f32x4 c) {
  return __builtin_amdgcn_mfma_f32_16x16x32_bf16(a, b, c, 0, 0, 0);
}

// ---------------------------------------------------------------------------
// Projection: Y = X @ W^T for Wq, Wk, Wv in one pass.
// X fp32 [B*S][768] -> Qs bf16 [B*S][64] (pre-scaled 1/8), Ks bf16 [B*S][64],
// Vt bf16 [B*64][S] (transposed for PV fragment loads).
// grid = B*S/64 blocks, 256 threads (4 waves), each block does 64 rows.
// ---------------------------------------------------------------------------
__global__ __launch_bounds__(256) void proj_kernel(
    const float* __restrict__ x,
    const float* __restrict__ Wq,
    const float* __restrict__ Wk,
    const float* __restrict__ Wv,
    bf16* __restrict__ Qs, bf16* __restrict__ Ks, bf16* __restrict__ Vt)
{
  __shared__ bf16 Xs[64][40];    // stride 40 elems (80B) to spread banks
  __shared__ bf16 Ws[192][40];

  const int t    = threadIdx.x;
  const int lane = t & 63;
  const int w    = t >> 6;
  const int r    = lane & 15;
  const int g    = lane >> 4;
  const long long row0 = (long long)blockIdx.x * 64;

  f32x4 acc[12];
  #pragma unroll
  for (int i = 0; i < 12; ++i) acc[i] = f32x4{0.f, 0.f, 0.f, 0.f};

  const int xr = t >> 2;         // 0..63
  const int xc = (t & 3) * 8;    // 0,8,16,24

  for (int k0 = 0; k0 < EMBED; k0 += 32) {
    // ---- stage X tile (fp32 -> bf16) ----
    {
      const float* src = x + (row0 + xr) * EMBED + k0 + xc;
      float4 a = *reinterpret_cast<const float4*>(src);
      float4 b = *reinterpret_cast<const float4*>(src + 4);
      bf16x8 v;
      v[0]=(bf16)a.x; v[1]=(bf16)a.y; v[2]=(bf16)a.z; v[3]=(bf16)a.w;
      v[4]=(bf16)b.x; v[5]=(bf16)b.y; v[6]=(bf16)b.z; v[7]=(bf16)b.w;
      *reinterpret_cast<bf16x8*>(&Xs[xr][xc]) = v;
    }
    // ---- stage W tiles (rows 0..63 = Wq, 64..127 = Wk, 128..191 = Wv) ----
    {
      const float* wsrcs[3] = {Wq + (long long)xr * EMBED + k0 + xc,
                               Wk + (long long)xr * EMBED + k0 + xc,
                               Wv + (long long)xr * EMBED + k0 + xc};
      #pragma unroll
      for (int m = 0; m < 3; ++m) {
        float4 a = *reinterpret_cast<const float4*>(wsrcs[m]);
        float4 b = *reinterpret_cast<const float4*>(wsrcs[m] + 4);
        bf16x8 v;
        v[0]=(bf16)a.x; v[1]=(bf16)a.y; v[2]=(bf16)a.z; v[3]=(bf16)a.w;
        v[4]=(bf16)b.x; v[5]=(bf16)b.y; v[6]=(bf16)b.z; v[7]=(bf16)b.w;
        *reinterpret_cast<bf16x8*>(&Ws[m * 64 + xr][xc]) = v;
      }
    }
    __syncthreads();
    // ---- MFMA: wave w computes rows [w*16, w*16+16) x 192 cols ----
    bf16x8 afrag = *reinterpret_cast<const bf16x8*>(&Xs[w * 16 + r][g * 8]);
    #pragma unroll
    for (int n = 0; n < 12; ++n) {
      bf16x8 bfrag = *reinterpret_cast<const bf16x8*>(&Ws[n * 16 + r][g * 8]);
      acc[n] = mfma16(afrag, bfrag, acc[n]);
    }
    __syncthreads();
  }

  // ---- epilogue: D layout row=(g*4+j), col=r ----
  const long long rowbase = row0 + w * 16 + g * 4;
  #pragma unroll
  for (int n = 0; n < 4; ++n) {
    #pragma unroll
    for (int j = 0; j < 4; ++j) {
      Qs[(rowbase + j) * ADIM + n * 16 + r] = (bf16)(acc[n][j] * 0.125f);
      Ks[(rowbase + j) * ADIM + n * 16 + r] = (bf16)(acc[4 + n][j]);
    }
  }
  const int bb = (int)(rowbase >> 12);    // /SEQ
  const int ss = (int)(rowbase & 4095);
  #pragma unroll
  for (int n = 0; n < 4; ++n) {
    const int d = n * 16 + r;
    bf16x4 pack;
    pack[0] = (bf16)(acc[8 + n][0]);
    pack[1] = (bf16)(acc[8 + n][1]);
    pack[2] = (bf16)(acc[8 + n][2]);
    pack[3] = (bf16)(acc[8 + n][3]);
    *reinterpret_cast<bf16x4*>(&Vt[((long long)bb * 64 + d) * SEQ + ss]) = pack;
  }
}

// ---------------------------------------------------------------------------
// Flash attention, causal. 1 wave per block; each wave handles two paired
// 16-row q-tiles (i, 255-i) of one batch for load balance.
// grid = B * (S/16) / 2 = 512 blocks of 64 threads.
// ---------------------------------------------------------------------------
__global__ __launch_bounds__(64) void attn_kernel(
    const bf16* __restrict__ Qs, const bf16* __restrict__ Ks,
    const bf16* __restrict__ Vt, float* __restrict__ out)
{
  __shared__ bf16 Pbuf[16][40];   // padded stride

  const int lane = threadIdx.x & 63;
  const int r = lane & 15;
  const int g = lane >> 4;
  const int wid = blockIdx.x;        // [0, 512)
  const int b   = wid >> 7;          // 128 pairs per batch
  const int i   = wid & 127;

  const bf16* Qb = Qs + (long long)b * SEQ * ADIM;
  const bf16* Kb = Ks + (long long)b * SEQ * ADIM;
  const bf16* Vb = Vt + (long long)b * ADIM * SEQ;
  float* outb    = out + (long long)b * SEQ * ADIM;

  const float L2E = 1.44269504088896340736f;

  for (int ti = 0; ti < 2; ++ti) {
    const int qt = (ti == 0) ? i : (255 - i);
    const int qb = qt * 16;

    // Q fragments (16 rows x 64 dims -> 2 k-chunks)
    bf16x8 qf0 = *reinterpret_cast<const bf16x8*>(Qb + (qb + r) * ADIM +  0 + g * 8);
    bf16x8 qf1 = *reinterpret_cast<const bf16x8*>(Qb + (qb + r) * ADIM + 32 + g * 8);

    f32x4 o[4];
    #pragma unroll
    for (int c = 0; c < 4; ++c) o[c] = f32x4{0.f, 0.f, 0.f, 0.f};
    float m[4], l[4];
    #pragma unroll
    for (int j = 0; j < 4; ++j) { m[j] = -INFINITY; l[j] = 0.f; }

    const int nt = ((qb + 15) >> 5) + 1;   // kv tiles of 32 covering [0, qb+15]
    for (int tkv = 0; tkv < nt; ++tkv) {
      const int kv0 = tkv * 32;

      // issue K and V fragment loads up front (V arrives during softmax)
      bf16x8 kf[2][2], vf[4];
      #pragma unroll
      for (int nc = 0; nc < 2; ++nc)
        #pragma unroll
        for (int kc = 0; kc < 2; ++kc)
          kf[nc][kc] = *reinterpret_cast<const bf16x8*>(
              Kb + (kv0 + nc * 16 + r) * ADIM + kc * 32 + g * 8);
      #pragma unroll
      for (int c = 0; c < 4; ++c)
        vf[c] = *reinterpret_cast<const bf16x8*>(
            Vb + (c * 16 + r) * SEQ + kv0 + g * 8);

      // S = Q K^T (scale already folded into Q)
      f32x4 sacc[2];
      sacc[0] = f32x4{0.f, 0.f, 0.f, 0.f};
      sacc[1] = f32x4{0.f, 0.f, 0.f, 0.f};
      #pragma unroll
      for (int nc = 0; nc < 2; ++nc) {
        sacc[nc] = mfma16(qf0, kf[nc][0], sacc[nc]);
        sacc[nc] = mfma16(qf1, kf[nc][1], sacc[nc]);
      }

      // causal mask (only tiles overlapping the diagonal)
      if (kv0 + 31 > qb) {
        #pragma unroll
        for (int nc = 0; nc < 2; ++nc) {
          const int key = kv0 + nc * 16 + r;
          #pragma unroll
          for (int j = 0; j < 4; ++j) {
            const int q = qb + g * 4 + j;
            if (key > q) sacc[nc][j] = -INFINITY;
          }
        }
      }

      // online softmax per row j (rows live across 16-lane groups)
      float p0[4], p1[4];
      #pragma unroll
      for (int j = 0; j < 4; ++j) {
        float tm = fmaxf(sacc[0][j], sacc[1][j]);
        tm = fmaxf(tm, __shfl_xor(tm, 1));
        tm = fmaxf(tm, __shfl_xor(tm, 2));
        tm = fmaxf(tm, __shfl_xor(tm, 4));
        tm = fmaxf(tm, __shfl_xor(tm, 8));
        const float mn = fmaxf(m[j], tm);
        const float sc = exp2f((m[j] - mn) * L2E);
        m[j] = mn;
        const float e0 = exp2f((sacc[0][j] - mn) * L2E);
        const float e1 = exp2f((sacc[1][j] - mn) * L2E);
        float rs = e0 + e1;
        rs += __shfl_xor(rs, 1);
        rs += __shfl_xor(rs, 2);
        rs += __shfl_xor(rs, 4);
        rs += __shfl_xor(rs, 8);
        l[j] = l[j] * sc + rs;
        #pragma unroll
        for (int c = 0; c < 4; ++c) o[c][j] *= sc;
        p0[j] = e0;
        p1[j] = e1;
      }

      // P -> LDS (D layout) -> A fragment
      #pragma unroll
      for (int j = 0; j < 4; ++j) {
        Pbuf[g * 4 + j][r]      = (bf16)p0[j];
        Pbuf[g * 4 + j][16 + r] = (bf16)p1[j];
      }
      bf16x8 pf = *reinterpret_cast<const bf16x8*>(&Pbuf[r][g * 8]);

      // O += P V
      #pragma unroll
      for (int c = 0; c < 4; ++c) o[c] = mfma16(pf, vf[c], o[c]);
    }

    // epilogue: normalize and store fp32
    #pragma unroll
    for (int j = 0; j < 4; ++j) {
      const float inv = 1.0f / l[j];
      const int q = qb + g * 4 + j;
      #pragma unroll
      for (int c = 0; c < 4; ++c)
        outb[(long long)q * ADIM + c * 16 + r] = o[c][j] * inv;
    }
  }
}

extern "C" void kernel_launch(void* const* d_in, const int* in_sizes, int n_in,
                              void* d_out, int out_size, void* d_ws, size_t ws_size,
                              hipStream_t stream) {
  const float* x  = (const float*)d_in[0];
  const float* Wq = (const float*)d_in[1];
  const float* Wk = (const float*)d_in[2];
  const float* Wv = (const float*)d_in[3];

  const size_t qkvElems = (size_t)NBATCH * SEQ * ADIM;   // 1M elems each
  bf16* Qs = (bf16*)d_ws;
  bf16* Ks = Qs + qkvElems;
  bf16* Vt = Ks + qkvElems;

  proj_kernel<<<NBATCH * SEQ / 64, 256, 0, stream>>>(x, Wq, Wk, Wv, Qs, Ks, Vt);
  attn_kernel<<<NBATCH * (SEQ / 16) / 2, 64, 0, stream>>>(Qs, Ks, Vt, (float*)d_out);
}

// Round 2
// 93.772 us; speedup vs baseline: 2.1104x; 2.1104x over previous
//
#include <hip/hip_runtime.h>
#include <hip/hip_bf16.h>
#include <math.h>

#define EMBED  768
#define SEQ    4096
#define ADIM   64
#define NBATCH 4

typedef __bf16 bf16;
typedef __attribute__((ext_vector_type(8))) __bf16 bf16x8;
typedef __attribute__((ext_vector_type(4))) __bf16 bf16x4;
typedef __attribute__((ext_vector_type(4))) float f32x4;

__device__ __forceinline__ f32x4 mfma16(bf16x8 a, bf16x8 b, f32x4 c) {
  return __builtin_amdgcn_mfma_f32_16x16x32_bf16(a, b, c, 0, 0, 0);
}

// ---------------------------------------------------------------------------
// Projection: Y = X @ W^T for Wq, Wk, Wv in one pass.
// X fp32 [B*S][768] -> Qs bf16 [B*S][64] (pre-scaled by 0.125*log2e),
// Ks bf16 [B*S][64], Vt bf16 [B*64][S] (transposed for PV fragment loads).
// ---------------------------------------------------------------------------
__global__ __launch_bounds__(256) void proj_kernel(
    const float* __restrict__ x,
    const float* __restrict__ Wq,
    const float* __restrict__ Wk,
    const float* __restrict__ Wv,
    bf16* __restrict__ Qs, bf16* __restrict__ Ks, bf16* __restrict__ Vt)
{
  __shared__ bf16 Xs[64][40];
  __shared__ bf16 Ws[192][40];

  const int t    = threadIdx.x;
  const int lane = t & 63;
  const int w    = t >> 6;
  const int r    = lane & 15;
  const int g    = lane >> 4;
  const long long row0 = (long long)blockIdx.x * 64;

  f32x4 acc[12];
  #pragma unroll
  for (int i = 0; i < 12; ++i) acc[i] = f32x4{0.f, 0.f, 0.f, 0.f};

  const int xr = t >> 2;
  const int xc = (t & 3) * 8;

  for (int k0 = 0; k0 < EMBED; k0 += 32) {
    {
      const float* src = x + (row0 + xr) * EMBED + k0 + xc;
      float4 a = *reinterpret_cast<const float4*>(src);
      float4 b = *reinterpret_cast<const float4*>(src + 4);
      bf16x8 v;
      v[0]=(bf16)a.x; v[1]=(bf16)a.y; v[2]=(bf16)a.z; v[3]=(bf16)a.w;
      v[4]=(bf16)b.x; v[5]=(bf16)b.y; v[6]=(bf16)b.z; v[7]=(bf16)b.w;
      *reinterpret_cast<bf16x8*>(&Xs[xr][xc]) = v;
    }
    {
      const float* wsrcs[3] = {Wq + (long long)xr * EMBED + k0 + xc,
                               Wk + (long long)xr * EMBED + k0 + xc,
                               Wv + (long long)xr * EMBED + k0 + xc};
      #pragma unroll
      for (int m = 0; m < 3; ++m) {
        float4 a = *reinterpret_cast<const float4*>(wsrcs[m]);
        float4 b = *reinterpret_cast<const float4*>(wsrcs[m] + 4);
        bf16x8 v;
        v[0]=(bf16)a.x; v[1]=(bf16)a.y; v[2]=(bf16)a.z; v[3]=(bf16)a.w;
        v[4]=(bf16)b.x; v[5]=(bf16)b.y; v[6]=(bf16)b.z; v[7]=(bf16)b.w;
        *reinterpret_cast<bf16x8*>(&Ws[m * 64 + xr][xc]) = v;
      }
    }
    __syncthreads();
    bf16x8 afrag = *reinterpret_cast<const bf16x8*>(&Xs[w * 16 + r][g * 8]);
    #pragma unroll
    for (int n = 0; n < 12; ++n) {
      bf16x8 bfrag = *reinterpret_cast<const bf16x8*>(&Ws[n * 16 + r][g * 8]);
      acc[n] = mfma16(afrag, bfrag, acc[n]);
    }
    __syncthreads();
  }

  // Q pre-scale: 1/sqrt(64) * log2(e), so attn softmax can use exp2 natively.
  const float QSCALE = 0.125f * 1.44269504088896340736f;
  const long long rowbase = row0 + w * 16 + g * 4;
  #pragma unroll
  for (int n = 0; n < 4; ++n) {
    #pragma unroll
    for (int j = 0; j < 4; ++j) {
      Qs[(rowbase + j) * ADIM + n * 16 + r] = (bf16)(acc[n][j] * QSCALE);
      Ks[(rowbase + j) * ADIM + n * 16 + r] = (bf16)(acc[4 + n][j]);
    }
  }
  const int bb = (int)(rowbase >> 12);
  const int ss = (int)(rowbase & 4095);
  #pragma unroll
  for (int n = 0; n < 4; ++n) {
    const int d = n * 16 + r;
    bf16x4 pack;
    pack[0] = (bf16)(acc[8 + n][0]);
    pack[1] = (bf16)(acc[8 + n][1]);
    pack[2] = (bf16)(acc[8 + n][2]);
    pack[3] = (bf16)(acc[8 + n][3]);
    *reinterpret_cast<bf16x4*>(&Vt[((long long)bb * 64 + d) * SEQ + ss]) = pack;
  }
}

// ---------------------------------------------------------------------------
// Flash attention, causal, swapped-operand layout (q = lane&15 everywhere).
// 512 blocks x 8 waves. Block owns q-tile pair (i, 255-i) of one batch;
// the 8 waves split kv-tiles (stride 8) and merge partials in LDS.
// ---------------------------------------------------------------------------
__global__ __launch_bounds__(512, 4) void attn_kernel(
    const bf16* __restrict__ Qs, const bf16* __restrict__ Ks,
    const bf16* __restrict__ Vt, float* __restrict__ out)
{
  __shared__ bf16  Pbuf[8][16][40];
  __shared__ float Olds[8][16][72];
  __shared__ float Mlds[8][16];
  __shared__ float Llds[8][16];

  const int t    = threadIdx.x;
  const int lane = t & 63;
  const int w    = t >> 6;
  const int r    = lane & 15;
  const int g    = lane >> 4;
  const int wid  = blockIdx.x;
  const int b    = wid >> 7;
  const int i    = wid & 127;

  const bf16* Qb = Qs + (long long)b * SEQ * ADIM;
  const bf16* Kb = Ks + (long long)b * SEQ * ADIM;
  const bf16* Vb = Vt + (long long)b * ADIM * SEQ;
  float* outb    = out + (long long)b * SEQ * ADIM;

  for (int ti = 0; ti < 2; ++ti) {
    const int qt = ti ? (255 - i) : i;
    const int qb = qt * 16;

    // Q as B-operand: lane(r,g) holds Q[qb+r][g*8+e]
    bf16x8 qf0 = *reinterpret_cast<const bf16x8*>(Qb + (qb + r) * ADIM +  0 + g * 8);
    bf16x8 qf1 = *reinterpret_cast<const bf16x8*>(Qb + (qb + r) * ADIM + 32 + g * 8);

    f32x4 o[4];
    #pragma unroll
    for (int c = 0; c < 4; ++c) o[c] = f32x4{0.f, 0.f, 0.f, 0.f};
    float m = -INFINITY, l = 0.f;

    const int nt = ((qb + 15) >> 5) + 1;
    for (int tkv = w; tkv < nt; tkv += 8) {
      const int kv0 = tkv * 32;

      // K as A-operand: lane(r,g) holds K[kv0+nc*16+r][kc*32+g*8+e]
      bf16x8 kf[2][2], vf[4];
      #pragma unroll
      for (int nc = 0; nc < 2; ++nc)
        #pragma unroll
        for (int kc = 0; kc < 2; ++kc)
          kf[nc][kc] = *reinterpret_cast<const bf16x8*>(
              Kb + (kv0 + nc * 16 + r) * ADIM + kc * 32 + g * 8);
      #pragma unroll
      for (int c = 0; c < 4; ++c)
        vf[c] = *reinterpret_cast<const bf16x8*>(
            Vb + (c * 16 + r) * SEQ + kv0 + g * 8);

      // S^T = K Q^T: lane(r,g) gets S[key=kv0+nc*16+g*4+j][q=qb+r]
      f32x4 sacc[2];
      sacc[0] = f32x4{0.f, 0.f, 0.f, 0.f};
      sacc[1] = f32x4{0.f, 0.f, 0.f, 0.f};
      sacc[0] = mfma16(kf[0][0], qf0, sacc[0]);
      sacc[0] = mfma16(kf[0][1], qf1, sacc[0]);
      sacc[1] = mfma16(kf[1][0], qf0, sacc[1]);
      sacc[1] = mfma16(kf[1][1], qf1, sacc[1]);

      // causal mask: key > q -> -inf
      if (kv0 + 31 > qb) {
        #pragma unroll
        for (int nc = 0; nc < 2; ++nc)
          #pragma unroll
          for (int j = 0; j < 4; ++j)
            if (kv0 + nc * 16 + g * 4 + j > qb + r) sacc[nc][j] = -INFINITY;
      }

      // per-lane online softmax (q = r): 2 shuffles for max, 2 for sum
      float tmax = fmaxf(fmaxf(fmaxf(sacc[0][0], sacc[0][1]), fmaxf(sacc[0][2], sacc[0][3])),
                         fmaxf(fmaxf(sacc[1][0], sacc[1][1]), fmaxf(sacc[1][2], sacc[1][3])));
      tmax = fmaxf(tmax, __shfl_xor(tmax, 16));
      tmax = fmaxf(tmax, __shfl_xor(tmax, 32));
      const float mn  = fmaxf(m, tmax);
      const float mne = (mn == -INFINITY) ? 0.f : mn;  // all-masked guard
      const float sc  = exp2f(m - mne);
      float p[2][4];
      float rs = 0.f;
      #pragma unroll
      for (int nc = 0; nc < 2; ++nc) {
        #pragma unroll
        for (int j = 0; j < 4; ++j) {
          p[nc][j] = exp2f(sacc[nc][j] - mne);
          rs += p[nc][j];
        }
      }
      // P^T -> per-wave LDS (regroup g*4+j -> g*8+e), no barrier needed
      #pragma unroll
      for (int nc = 0; nc < 2; ++nc) {
        bf16x4 pk;
        pk[0] = (bf16)p[nc][0]; pk[1] = (bf16)p[nc][1];
        pk[2] = (bf16)p[nc][2]; pk[3] = (bf16)p[nc][3];
        *reinterpret_cast<bf16x4*>(&Pbuf[w][r][nc * 16 + g * 4]) = pk;
      }
      rs += __shfl_xor(rs, 16);
      rs += __shfl_xor(rs, 32);
      l = l * sc + rs;
      m = mn;
      #pragma unroll
      for (int c = 0; c < 4; ++c) {
        o[c][0] *= sc; o[c][1] *= sc; o[c][2] *= sc; o[c][3] *= sc;
      }

      bf16x8 pf = *reinterpret_cast<const bf16x8*>(&Pbuf[w][r][g * 8]);
      // O^T += V^T P: lane(r,g) accumulates O[q=qb+r][d=c*16+g*4+j]
      #pragma unroll
      for (int c = 0; c < 4; ++c) o[c] = mfma16(vf[c], pf, o[c]);
    }

    // publish partials
    #pragma unroll
    for (int c = 0; c < 4; ++c)
      *reinterpret_cast<f32x4*>(&Olds[w][r][c * 16 + g * 4]) = o[c];
    if (g == 0) { Mlds[w][r] = m; Llds[w][r] = l; }
    __syncthreads();

    // combine: wave w merges d-slice [w*8, w*8+8), lane(r,g) does 2 dims
    {
      const int dbase = w * 8 + g * 2;
      float mf = Mlds[0][r];
      #pragma unroll
      for (int w2 = 1; w2 < 8; ++w2) mf = fmaxf(mf, Mlds[w2][r]);
      float lf = 0.f, ox = 0.f, oy = 0.f;
      #pragma unroll
      for (int w2 = 0; w2 < 8; ++w2) {
        const float s = exp2f(Mlds[w2][r] - mf);
        lf += s * Llds[w2][r];
        const float2 ov = *reinterpret_cast<const float2*>(&Olds[w2][r][dbase]);
        ox += s * ov.x;
        oy += s * ov.y;
      }
      const float inv = 1.f / lf;
      float2 res; res.x = ox * inv; res.y = oy * inv;
      *reinterpret_cast<float2*>(outb + (long long)(qb + r) * ADIM + dbase) = res;
    }
    __syncthreads();  // protect LDS reuse by next q-tile
  }
}

extern "C" void kernel_launch(void* const* d_in, const int* in_sizes, int n_in,
                              void* d_out, int out_size, void* d_ws, size_t ws_size,
                              hipStream_t stream) {
  const float* x  = (const float*)d_in[0];
  const float* Wq = (const float*)d_in[1];
  const float* Wk = (const float*)d_in[2];
  const float* Wv = (const float*)d_in[3];

  const size_t qkvElems = (size_t)NBATCH * SEQ * ADIM;
  bf16* Qs = (bf16*)d_ws;
  bf16* Ks = Qs + qkvElems;
  bf16* Vt = Ks + qkvElems;

  proj_kernel<<<NBATCH * SEQ / 64, 256, 0, stream>>>(x, Wq, Wk, Wv, Qs, Ks, Vt);
  attn_kernel<<<NBATCH * (SEQ / 16) / 2, 512, 0, stream>>>(Qs, Ks, Vt, (float*)d_out);
}

// Round 3
// 60.567 us; speedup vs baseline: 3.2674x; 1.5482x over previous
//
#include <hip/hip_runtime.h>
#include <hip/hip_bf16.h>
#include <math.h>

#define EMBED  768
#define SEQ    4096
#define ADIM   64
#define NBATCH 4
#define WELEMS (ADIM * EMBED)          // 49152 per matrix
#define QSCALE (0.125f * 1.44269504088896340736f)

typedef __bf16 bf16;
typedef __attribute__((ext_vector_type(8))) __bf16 bf16x8;
typedef __attribute__((ext_vector_type(4))) __bf16 bf16x4;
typedef __attribute__((ext_vector_type(4))) float f32x4;
typedef __attribute__((ext_vector_type(16))) float f32x16;

__device__ __forceinline__ f32x4 mfma16(bf16x8 a, bf16x8 b, f32x4 c) {
  return __builtin_amdgcn_mfma_f32_16x16x32_bf16(a, b, c, 0, 0, 0);
}
__device__ __forceinline__ f32x16 mfma32(bf16x8 a, bf16x8 b, f32x16 c) {
  return __builtin_amdgcn_mfma_f32_32x32x16_bf16(a, b, c, 0, 0, 0);
}
__device__ __forceinline__ unsigned cvtpk(float lo, float hi) {
  unsigned d;
  asm("v_cvt_pk_bf16_f32 %0, %1, %2" : "=v"(d) : "v"(lo), "v"(hi));
  return d;
}

// ---------------------------------------------------------------------------
// W fp32 -> bf16 once (Q-scale folded into Wq). Wb = [3][ADIM][EMBED] bf16.
// ---------------------------------------------------------------------------
__global__ __launch_bounds__(256) void wconv_kernel(
    const float* __restrict__ Wq, const float* __restrict__ Wk,
    const float* __restrict__ Wv, bf16* __restrict__ Wb)
{
  const int gid = blockIdx.x * 256 + threadIdx.x;   // 36864 threads, 4 elems each
  const int m   = gid / (WELEMS / 4);
  const int off = (gid % (WELEMS / 4)) * 4;
  const float* src = (m == 0) ? Wq : ((m == 1) ? Wk : Wv);
  const float  sc  = (m == 0) ? QSCALE : 1.0f;
  float4 v = *reinterpret_cast<const float4*>(src + off);
  bf16x4 o;
  o[0] = (bf16)(v.x * sc); o[1] = (bf16)(v.y * sc);
  o[2] = (bf16)(v.z * sc); o[3] = (bf16)(v.w * sc);
  *reinterpret_cast<bf16x4*>(Wb + (size_t)m * WELEMS + off) = o;
}

// ---------------------------------------------------------------------------
// Projection: Y = X @ W^T for all 3 W, double-buffered 2-phase pipeline.
// X fp32 [B*S][768]; Wb bf16. Outputs: Qs/Ks bf16 [B*S][64], Vt bf16 [B*64][S].
// ---------------------------------------------------------------------------
__global__ __launch_bounds__(256) void proj_kernel(
    const float* __restrict__ x, const bf16* __restrict__ Wb,
    bf16* __restrict__ Qs, bf16* __restrict__ Ks, bf16* __restrict__ Vt)
{
  __shared__ bf16 Xs[2][64][40];
  __shared__ bf16 Ws[2][192][40];

  const int t    = threadIdx.x;
  const int lane = t & 63;
  const int w    = t >> 6;
  const int r    = lane & 15;
  const int g    = lane >> 4;
  const long long row0 = (long long)blockIdx.x * 64;

  f32x4 acc[12];
  #pragma unroll
  for (int i = 0; i < 12; ++i) acc[i] = f32x4{0.f, 0.f, 0.f, 0.f};

  const int xr = t >> 2;
  const int xc = (t & 3) * 8;
  const float* xsrc = x + (row0 + xr) * EMBED + xc;
  const bf16*  wsrc = Wb + xr * EMBED + xc;

  // prologue: stage k0 = 0 into buffer 0
  {
    float4 xa = *reinterpret_cast<const float4*>(xsrc);
    float4 xb = *reinterpret_cast<const float4*>(xsrc + 4);
    bf16x8 w0 = *reinterpret_cast<const bf16x8*>(wsrc);
    bf16x8 w1 = *reinterpret_cast<const bf16x8*>(wsrc + WELEMS);
    bf16x8 w2 = *reinterpret_cast<const bf16x8*>(wsrc + 2 * WELEMS);
    bf16x8 xv;
    xv[0]=(bf16)xa.x; xv[1]=(bf16)xa.y; xv[2]=(bf16)xa.z; xv[3]=(bf16)xa.w;
    xv[4]=(bf16)xb.x; xv[5]=(bf16)xb.y; xv[6]=(bf16)xb.z; xv[7]=(bf16)xb.w;
    *reinterpret_cast<bf16x8*>(&Xs[0][xr][xc]) = xv;
    *reinterpret_cast<bf16x8*>(&Ws[0][xr][xc]) = w0;
    *reinterpret_cast<bf16x8*>(&Ws[0][64 + xr][xc]) = w1;
    *reinterpret_cast<bf16x8*>(&Ws[0][128 + xr][xc]) = w2;
  }
  __syncthreads();

  int cur = 0;
  for (int kt = 0; kt < 24; ++kt) {
    const int k0n = (kt + 1) * 32;
    const bool pf = kt < 23;
    float4 xa, xb; bf16x8 w0, w1, w2;
    if (pf) {   // issue next-tile loads (in flight during MFMA)
      xa = *reinterpret_cast<const float4*>(xsrc + k0n);
      xb = *reinterpret_cast<const float4*>(xsrc + k0n + 4);
      w0 = *reinterpret_cast<const bf16x8*>(wsrc + k0n);
      w1 = *reinterpret_cast<const bf16x8*>(wsrc + WELEMS + k0n);
      w2 = *reinterpret_cast<const bf16x8*>(wsrc + 2 * WELEMS + k0n);
    }
    bf16x8 afrag = *reinterpret_cast<const bf16x8*>(&Xs[cur][w * 16 + r][g * 8]);
    #pragma unroll
    for (int n = 0; n < 12; ++n) {
      bf16x8 bfrag = *reinterpret_cast<const bf16x8*>(&Ws[cur][n * 16 + r][g * 8]);
      acc[n] = mfma16(afrag, bfrag, acc[n]);
    }
    if (pf) {   // land next tile into the other buffer
      bf16x8 xv;
      xv[0]=(bf16)xa.x; xv[1]=(bf16)xa.y; xv[2]=(bf16)xa.z; xv[3]=(bf16)xa.w;
      xv[4]=(bf16)xb.x; xv[5]=(bf16)xb.y; xv[6]=(bf16)xb.z; xv[7]=(bf16)xb.w;
      *reinterpret_cast<bf16x8*>(&Xs[cur ^ 1][xr][xc]) = xv;
      *reinterpret_cast<bf16x8*>(&Ws[cur ^ 1][xr][xc]) = w0;
      *reinterpret_cast<bf16x8*>(&Ws[cur ^ 1][64 + xr][xc]) = w1;
      *reinterpret_cast<bf16x8*>(&Ws[cur ^ 1][128 + xr][xc]) = w2;
    }
    __syncthreads();
    cur ^= 1;
  }

  // epilogue: 16x16 D layout row=(g*4+j), col=r  (Q scale folded into Wq)
  const long long rowbase = row0 + w * 16 + g * 4;
  #pragma unroll
  for (int n = 0; n < 4; ++n) {
    #pragma unroll
    for (int j = 0; j < 4; ++j) {
      Qs[(rowbase + j) * ADIM + n * 16 + r] = (bf16)(acc[n][j]);
      Ks[(rowbase + j) * ADIM + n * 16 + r] = (bf16)(acc[4 + n][j]);
    }
  }
  const int bb = (int)(rowbase >> 12);
  const int ss = (int)(rowbase & 4095);
  #pragma unroll
  for (int n = 0; n < 4; ++n) {
    const int d = n * 16 + r;
    bf16x4 pack;
    pack[0] = (bf16)(acc[8 + n][0]);
    pack[1] = (bf16)(acc[8 + n][1]);
    pack[2] = (bf16)(acc[8 + n][2]);
    pack[3] = (bf16)(acc[8 + n][3]);
    *reinterpret_cast<bf16x4*>(&Vt[((long long)bb * 64 + d) * SEQ + ss]) = pack;
  }
}

// ---------------------------------------------------------------------------
// Flash attention, causal. 32x32x16 MFMA, swapped operands: q = lane&31.
// 512 blocks x 8 waves; block owns one 32-row q-tile; waves kv-split (stride 8)
// and merge partials in LDS. Dispatch pairs (qt, 127-qt) for CU balance.
// ---------------------------------------------------------------------------
__global__ __launch_bounds__(512, 4) void attn_kernel(
    const bf16* __restrict__ Qs, const bf16* __restrict__ Ks,
    const bf16* __restrict__ Vt, float* __restrict__ out)
{
  __shared__ float Olds[8][32][68];
  __shared__ float Mlds[8][32];
  __shared__ float Llds[8][32];

  const int t    = threadIdx.x;
  const int lane = t & 63;
  const int w    = t >> 6;
  const int q    = lane & 31;
  const int h    = lane >> 5;
  const int bi   = blockIdx.x;
  int b, qt;
  if (bi < 256) { b = bi >> 7;               qt = bi & 127; }
  else          { b = 2 + ((bi - 256) >> 7); qt = 127 - (bi & 127); }
  const int qb = qt * 32;

  const bf16* Qb = Qs + (long long)b * SEQ * ADIM;
  const bf16* Kb = Ks + (long long)b * SEQ * ADIM;
  const bf16* Vb = Vt + (long long)b * ADIM * SEQ;

  // Q as B-operand: lane(q,h) holds Q[qb+q][kc*16 + h*8 + e]
  bf16x8 qf[4];
  #pragma unroll
  for (int kc = 0; kc < 4; ++kc)
    qf[kc] = *reinterpret_cast<const bf16x8*>(Qb + (qb + q) * ADIM + kc * 16 + h * 8);

  f32x16 o0 = {0,0,0,0,0,0,0,0,0,0,0,0,0,0,0,0};
  f32x16 o1 = {0,0,0,0,0,0,0,0,0,0,0,0,0,0,0,0};
  float m = -INFINITY, l = 0.f;

  const bf16* krow  = Kb + q * ADIM + h * 8;
  const bf16* vrow0 = Vb + (long long)q * SEQ + h * 8;
  const bf16* vrow1 = Vb + (long long)(32 + q) * SEQ + h * 8;

  int st = w;
  bf16x8 kf[4];
  if (st <= qt) {
    #pragma unroll
    for (int kc = 0; kc < 4; ++kc)
      kf[kc] = *reinterpret_cast<const bf16x8*>(krow + st * 32 * ADIM + kc * 16);
  }

  for (; st <= qt; st += 8) {
    const int kv0 = st * 32;

    // V for this tile (used ~after softmax; latency hidden)
    bf16x8 vf00 = *reinterpret_cast<const bf16x8*>(vrow0 + kv0);
    bf16x8 vf01 = *reinterpret_cast<const bf16x8*>(vrow0 + kv0 + 16);
    bf16x8 vf10 = *reinterpret_cast<const bf16x8*>(vrow1 + kv0);
    bf16x8 vf11 = *reinterpret_cast<const bf16x8*>(vrow1 + kv0 + 16);

    // S^T = K Q^T : lane(q,h) reg(i*4+j) = S[key=kv0+j+8i+4h][qb+q]
    f32x16 s = {0,0,0,0,0,0,0,0,0,0,0,0,0,0,0,0};
    s = mfma32(kf[0], qf[0], s);
    s = mfma32(kf[1], qf[1], s);
    s = mfma32(kf[2], qf[2], s);
    s = mfma32(kf[3], qf[3], s);

    // prefetch next K tile (in flight across softmax + PV)
    if (st + 8 <= qt) {
      #pragma unroll
      for (int kc = 0; kc < 4; ++kc)
        kf[kc] = *reinterpret_cast<const bf16x8*>(krow + (st + 8) * 32 * ADIM + kc * 16);
    }

    // causal mask — only the diagonal tile
    if (st == qt) {
      #pragma unroll
      for (int i = 0; i < 4; ++i)
        #pragma unroll
        for (int j = 0; j < 4; ++j)
          if (kv0 + j + 8 * i + 4 * h > qb + q) s[i * 4 + j] = -INFINITY;
    }

    // per-lane online softmax: 1 shuffle for max, 1 for sum
    float tm = s[0];
    #pragma unroll
    for (int rr = 1; rr < 16; ++rr) tm = fmaxf(tm, s[rr]);
    tm = fmaxf(tm, __shfl_xor(tm, 32));

    const bool skip = __all((m > -1e37f) && (tm <= m + 8.0f));  // defer-max
    float mne;
    if (skip) {
      mne = m;
    } else {
      const float mn = fmaxf(m, tm);
      mne = (mn == -INFINITY) ? 0.f : mn;
      const float sc = exp2f(m - mne);
      #pragma unroll
      for (int rr = 0; rr < 16; ++rr) { o0[rr] *= sc; o1[rr] *= sc; }
      l *= sc;
      m = mn;
    }

    float rs = 0.f;
    #pragma unroll
    for (int rr = 0; rr < 16; ++rr) { s[rr] = exp2f(s[rr] - mne); rs += s[rr]; }
    rs += __shfl_xor(rs, 32);
    l += rs;

    // P^T fragments in-register: word(e,e+1) pairs, cross-half via shfl_xor(32)
    unsigned a0 = cvtpk(s[0],  s[1]),  a1 = cvtpk(s[2],  s[3]);
    unsigned b0 = cvtpk(s[4],  s[5]),  b1 = cvtpk(s[6],  s[7]);
    unsigned c0 = cvtpk(s[8],  s[9]),  c1 = cvtpk(s[10], s[11]);
    unsigned d0 = cvtpk(s[12], s[13]), d1 = cvtpk(s[14], s[15]);
    unsigned a0x = __shfl_xor((int)a0, 32), a1x = __shfl_xor((int)a1, 32);
    unsigned b0x = __shfl_xor((int)b0, 32), b1x = __shfl_xor((int)b1, 32);
    unsigned c0x = __shfl_xor((int)c0, 32), c1x = __shfl_xor((int)c1, 32);
    unsigned d0x = __shfl_xor((int)d0, 32), d1x = __shfl_xor((int)d1, 32);
    union { unsigned u[4]; bf16x8 v; } pa0, pa1;
    pa0.u[0] = h ? b0x : a0;  pa0.u[1] = h ? b1x : a1;
    pa0.u[2] = h ? b0  : a0x; pa0.u[3] = h ? b1  : a1x;
    pa1.u[0] = h ? d0x : c0;  pa1.u[1] = h ? d1x : c1;
    pa1.u[2] = h ? d0  : c0x; pa1.u[3] = h ? d1  : c1x;

    // O^T += V^T P : lane(q,h) reg(i*4+j) = O[qb+q][d = dc*32 + j + 8i + 4h]
    o0 = mfma32(vf00, pa0.v, o0);
    o0 = mfma32(vf01, pa1.v, o0);
    o1 = mfma32(vf10, pa0.v, o1);
    o1 = mfma32(vf11, pa1.v, o1);
  }

  // publish partials (C/D layout: d = dc*32 + 8*r2 + 4*h + j)
  #pragma unroll
  for (int r2 = 0; r2 < 4; ++r2) {
    f32x4 v0, v1;
    v0[0]=o0[r2*4+0]; v0[1]=o0[r2*4+1]; v0[2]=o0[r2*4+2]; v0[3]=o0[r2*4+3];
    v1[0]=o1[r2*4+0]; v1[1]=o1[r2*4+1]; v1[2]=o1[r2*4+2]; v1[3]=o1[r2*4+3];
    *reinterpret_cast<f32x4*>(&Olds[w][q][8 * r2 + 4 * h])      = v0;
    *reinterpret_cast<f32x4*>(&Olds[w][q][32 + 8 * r2 + 4 * h]) = v1;
  }
  if (h == 0) { Mlds[w][q] = m; Llds[w][q] = l; }
  __syncthreads();

  // combine 8 partials: thread -> (q=t>>4, 4 dims at (t&15)*4)
  {
    const int cq = t >> 4;
    const int cd = (t & 15) * 4;
    float mf = Mlds[0][cq];
    #pragma unroll
    for (int w2 = 1; w2 < 8; ++w2) mf = fmaxf(mf, Mlds[w2][cq]);
    float lf = 0.f;
    f32x4 ov = {0.f, 0.f, 0.f, 0.f};
    #pragma unroll
    for (int w2 = 0; w2 < 8; ++w2) {
      const float sc = exp2f(Mlds[w2][cq] - mf);
      lf += sc * Llds[w2][cq];
      const f32x4 pv = *reinterpret_cast<const f32x4*>(&Olds[w2][cq][cd]);
      ov[0] += sc * pv[0]; ov[1] += sc * pv[1];
      ov[2] += sc * pv[2]; ov[3] += sc * pv[3];
    }
    const float inv = 1.f / lf;
    float4 res;
    res.x = ov[0] * inv; res.y = ov[1] * inv;
    res.z = ov[2] * inv; res.w = ov[3] * inv;
    *reinterpret_cast<float4*>(out + ((long long)b * SEQ + qb + cq) * ADIM + cd) = res;
  }
}

extern "C" void kernel_launch(void* const* d_in, const int* in_sizes, int n_in,
                              void* d_out, int out_size, void* d_ws, size_t ws_size,
                              hipStream_t stream) {
  const float* x  = (const float*)d_in[0];
  const float* Wq = (const float*)d_in[1];
  const float* Wk = (const float*)d_in[2];
  const float* Wv = (const float*)d_in[3];

  const size_t qkvElems = (size_t)NBATCH * SEQ * ADIM;
  bf16* Qs = (bf16*)d_ws;
  bf16* Ks = Qs + qkvElems;
  bf16* Vt = Ks + qkvElems;
  bf16* Wb = Vt + qkvElems;

  wconv_kernel<<<3 * WELEMS / 4 / 256, 256, 0, stream>>>(Wq, Wk, Wv, Wb);
  proj_kernel<<<NBATCH * SEQ / 64, 256, 0, stream>>>(x, Wb, Qs, Ks, Vt);
  attn_kernel<<<512, 512, 0, stream>>>(Qs, Ks, Vt, (float*)d_out);
}